// Round 13
// baseline (222.346 us; speedup 1.0000x reference)
//
#include <hip/hip_runtime.h>
#include <math.h>

#define NSLOTS 50
#define T 101
#define SEQ 2048
#define CHUNK 16

// v + dpp_permuted(v), pure VALU
template<int CTRL>
__device__ __forceinline__ float dpp_xadd(float v) {
    int x = __builtin_amdgcn_update_dpp(0, __float_as_int(v), CTRL, 0xF, 0xF, true);
    return v + __int_as_float(x);
}

// Full 64-lane sum -> wave-uniform scalar (validated r8-r12, absmax 0.0)
__device__ __forceinline__ float wsum64(float v) {
    v = dpp_xadd<0xB1>(v);    // xor 1
    v = dpp_xadd<0x4E>(v);    // xor 2
    v = dpp_xadd<0x141>(v);   // xor 4 (row_half_mirror)
    v = dpp_xadd<0x140>(v);   // xor 8 (row_mirror)
    v = dpp_xadd<0x142>(v);   // row_bcast15
    v = dpp_xadd<0x143>(v);   // row_bcast31
    int s = __builtin_amdgcn_readlane(__float_as_int(v), 63);
    return __int_as_float(s);
}

__device__ __forceinline__ void gl_lds(const float* g, float* lds) {
#if __has_builtin(__builtin_amdgcn_global_load_lds)
    __builtin_amdgcn_global_load_lds((const __attribute__((address_space(1))) void*)g,
        (__attribute__((address_space(3))) void*)lds, 4, 0, 0);
#else
    lds[threadIdx.x & 63] = *g;
#endif
}

__global__ __launch_bounds__(192, 1) void crf_nll_kernel(
    const float* __restrict__ feats,      // [B,S,T]
    const float* __restrict__ cdt,        // [3,5] log-probs
    const float* __restrict__ start_t,    // [T]
    const float* __restrict__ stop_t,     // [T]
    const int*   __restrict__ mask,       // [B,S]
    const int*   __restrict__ tags,       // [B,S]
    float*       __restrict__ out)        // [B]
{
    const int b = blockIdx.x, tid = threadIdx.x;
    const int wave = tid >> 6, l = tid & 63;
    const float* fb = feats + (size_t)b * SEQ * T;
    const int*   mb = mask + (size_t)b * SEQ;
    const int*   tb = tags + (size_t)b * SEQ;

    __shared__ float S[64 * 128];   // ring: step t -> slot (t-1)&63
    __shared__ float res[2];

    // ---- length (all waves; mask is a prefix of ones) ----
    float mc = 0.f;
    for (int t = l; t < SEQ; t += 64) mc += (float)mb[t];
    const int len    = (int)(wsum64(mc) + 0.5f);
    const int nsteps = len - 1;
    const int nper   = (nsteps + CHUNK - 1) / CHUNK;
    const int nfull  = nsteps / CHUNK;

    const float actm = (l < NSLOTS) ? 1.f : 0.f;
    const int aB = (2*l+1 <= 100) ? 2*l+1 : 100;
    const int aI = (2*l+2 <= 100) ? 2*l+2 : 100;
    const int s1 = (2*l+1 <= 100) ? 2*l+1 : 0;
    const int s2 = (2*l+2 <= 100) ? 2*l+2 : 0;

    const float pOO=__expf(cdt[0]),  pOB=__expf(cdt[1]),  pOI=__expf(cdt[2]);
    const float pBO=__expf(cdt[5]),  pBBs=__expf(cdt[6]), pBIs=__expf(cdt[7]),
                pBBd=__expf(cdt[8]), pBId=__expf(cdt[9]);
    const float pIO=__expf(cdt[10]), pIBs=__expf(cdt[11]), pIIs=__expf(cdt[12]),
                pIBd=__expf(cdt[13]), pIId=__expf(cdt[14]);
    const float dBB=pBBs-pBBd, dIB=pIBs-pIBd, dBI=pBIs-pBId, dII=pIIs-pIId;

    // consumer state (r9-verbatim semantics; NO/xO finish deferred one phase)
    float xB=0.f, xI=0.f, xO=1.f, accF=0.f;
    float NOp=1.f, rscp=1.f;      // pending NO and its rescale: xO(t) = NOp*rscp
    int accE = 0;
    // 4-phase rotating pipeline registers (steps t, t+1, t+2 resident)
    float fAB=0,fAI=0,fAO=0, fBB=0,fBI=0,fBO=0, fCB=0,fCI=0,fCO=0, fDB=0,fDI=0,fDO=0;
    int w3 = 0;                   // element offset of the row for step t+3
    float gs = 0.f;               // gold partial (wave 2)

    if (wave == 1) {
        #pragma unroll
        for (int k = 0; k < 2*CHUNK; ++k) {   // stage chunks 0,1 (steps 1..32)
            const float* row = fb + (size_t)(1 + k) * T;
            float* dst = &S[(size_t)k * 128];
            gl_lds(row + s1, dst);
            gl_lds(row + s2, dst + 64);
        }
    } else if (wave == 0) {
        float pO0 = fb[0] + start_t[0];
        xB = actm * __expf(fb[aB] + start_t[aB] - pO0);
        xI = actm * __expf(fb[aI] + start_t[aI] - pO0);
        accF = pO0;
    } else {
        if (l == 0) { int tg0 = tb[0]; gs = fb[tg0] + start_t[tg0]; }
    }
    __syncthreads();   // chunks 0,1 staged

    if (wave == 0) {   // pipeline fill: steps 1,2,3
        fAB = S[l];         fAI = S[64 + l];         fAO = S[50];
        fBB = S[128 + l];   fBI = S[128 + 64 + l];   fBO = S[128 + 50];
        fCB = S[256 + l];   fCI = S[256 + 64 + l];   fCO = S[256 + 50];
        w3  = 384;          // slot of step 4 (= ((1+2)&63)<<7)
    }

// One fully-pipelined step (r9 algebra). cur = step t's feats; reads step t+3
// into nxt. Off-chain work is distributed into the 6 DPP-stage gaps; NO/xO of
// this step is finished in the NEXT phase's first filler (it's only needed by
// fillers, never by the reduction chain).
#define PHASE(cB_,cI_,cO_, nB_,nI_,nO_)                                        \
    {                                                                          \
        float raB = dpp_xadd<0xB1>(xB);                                        \
        float raI = dpp_xadd<0xB1>(xI);                                        \
        xO = NOp * rscp;                      /* finish prev step's xO */      \
        w3 = (w3 + 128) & 8191;                                                \
        raB = dpp_xadd<0x4E>(raB);                                             \
        raI = dpp_xadd<0x4E>(raI);                                             \
        float pOBx = pOB * xO;                                                 \
        float pOIx = pOI * xO;                                                 \
        float pOOx = pOO * xO;                                                 \
        raB = dpp_xadd<0x141>(raB);                                            \
        raI = dpp_xadd<0x141>(raI);                                            \
        float uB = __builtin_fmaf(xB, dBB, __builtin_fmaf(xI, dIB, pOBx));     \
        float uI = __builtin_fmaf(xB, dBI, __builtin_fmaf(xI, dII, pOIx));     \
        raB = dpp_xadd<0x140>(raB);                                            \
        raI = dpp_xadd<0x140>(raI);                                            \
        float gB = actm * __expf(cB_ - cO_);                                   \
        float gI = actm * __expf(cI_ - cO_);                                   \
        raB = dpp_xadd<0x142>(raB);                                            \
        raI = dpp_xadd<0x142>(raI);                                            \
        nB_ = S[w3 + l];                                                       \
        nI_ = S[w3 + 64 + l];                                                  \
        nO_ = S[w3 + 50];                                                      \
        raB = dpp_xadd<0x143>(raB);                                            \
        raI = dpp_xadd<0x143>(raI);                                            \
        int   ke  = ((__float_as_int(xO) >> 23) & 0xFF) - 127;                 \
        float rsc = __int_as_float((127 - ke) << 23);                          \
        accE += ke;                                                            \
        accF += cO_;                                                           \
        float tXB = __int_as_float(__builtin_amdgcn_readlane(__float_as_int(raB), 63)); \
        float tXI = __int_as_float(__builtin_amdgcn_readlane(__float_as_int(raI), 63)); \
        float NB = gB * __builtin_fmaf(tXI, pIBd, __builtin_fmaf(tXB, pBBd, uB)); \
        float NI = gI * __builtin_fmaf(tXI, pIId, __builtin_fmaf(tXB, pBId, uI)); \
        xB = NB * rsc;                                                         \
        xI = NI * rsc;                                                         \
        NOp = __builtin_fmaf(tXI, pIO, __builtin_fmaf(tXB, pBO, pOOx));        \
        rscp = rsc;                                                            \
    }

    for (int p = 0; p < nper; ++p) {
        if (wave == 0) {
            if (p < nfull) {
                // 16 phases, 4-name rotation (16 % 4 == 0)
                PHASE(fAB,fAI,fAO, fDB,fDI,fDO)
                PHASE(fBB,fBI,fBO, fAB,fAI,fAO)
                PHASE(fCB,fCI,fCO, fBB,fBI,fBO)
                PHASE(fDB,fDI,fDO, fCB,fCI,fCO)
                PHASE(fAB,fAI,fAO, fDB,fDI,fDO)
                PHASE(fBB,fBI,fBO, fAB,fAI,fAO)
                PHASE(fCB,fCI,fCO, fBB,fBI,fBO)
                PHASE(fDB,fDI,fDO, fCB,fCI,fCO)
                PHASE(fAB,fAI,fAO, fDB,fDI,fDO)
                PHASE(fBB,fBI,fBO, fAB,fAI,fAO)
                PHASE(fCB,fCI,fCO, fBB,fBI,fBO)
                PHASE(fDB,fDI,fDO, fCB,fCI,fCO)
                PHASE(fAB,fAI,fAO, fDB,fDI,fDO)
                PHASE(fBB,fBI,fBO, fAB,fAI,fAO)
                PHASE(fCB,fCI,fCO, fBB,fBI,fBO)
                PHASE(fDB,fDI,fDO, fCB,fCI,fCO)
            } else {
                if (p == nfull) { xO = NOp * rscp; }   // finish last pipelined step
                // simple r9-style guarded body for the <=16 tail steps
                for (int k = 0; k < CHUNK; ++k) {
                    int t = 1 + p * CHUNK + k;
                    if (t <= nsteps) {
                        const float* row = &S[(size_t)(((t - 1) & 63)) << 7];
                        float fBv = row[l], fIv = row[64 + l], fOv = row[50];
                        float gB = actm * __expf(fBv - fOv);
                        float gI = actm * __expf(fIv - fOv);
                        float pOBx = pOB * xO, pOIx = pOI * xO, pOOx = pOO * xO;
                        float uB = __builtin_fmaf(xB, dBB, __builtin_fmaf(xI, dIB, pOBx));
                        float uI = __builtin_fmaf(xB, dBI, __builtin_fmaf(xI, dII, pOIx));
                        int   ke  = ((__float_as_int(xO) >> 23) & 0xFF) - 127;
                        float rsc = __int_as_float((127 - ke) << 23);
                        accE += ke; accF += fOv;
                        float XB = wsum64(xB);
                        float XI = wsum64(xI);
                        float NO = __builtin_fmaf(XI, pIO, __builtin_fmaf(XB, pBO, pOOx));
                        float NB = gB * __builtin_fmaf(XI, pIBd, __builtin_fmaf(XB, pBBd, uB));
                        float NI = gI * __builtin_fmaf(XI, pIId, __builtin_fmaf(XB, pBId, uI));
                        xB = NB * rsc; xI = NI * rsc; xO = NO * rsc;
                    }
                }
            }
        } else if (wave == 1) {
            const int ci = p + 2;                  // stage chunk p+2
            #pragma unroll
            for (int k = 0; k < CHUNK; ++k) {
                int t = 1 + ci * CHUNK + k;
                t = (t < SEQ) ? t : (SEQ - 1);     // clamp; rows beyond len unused
                const float* row = fb + (size_t)t * T;
                float* dst = &S[(size_t)((ci * CHUNK + k) & 63) * 128];
                gl_lds(row + s1, dst);
                gl_lds(row + s2, dst + 64);
            }
        } else {
            // gold wave: chunk p-1 (rows live until period p+1)
            if (p >= 1 && l < CHUNK) {
                int t = 1 + (p - 1) * CHUNK + l;
                if (t <= nsteps) {
                    int tg = tb[t], tp = tb[t - 1];
                    int c1 = (tp == 0) ? 0 : ((tp & 1) ? 1 : 2);
                    int c2 = (tg == 0) ? 0 : ((tg & 1) ? 1 : 2);
                    int si = (tp - 1) >> 1, sj = (tg - 1) >> 1;
                    int t1 = (tp != 0 && si != sj) ? ((c2 == 0) ? 0 : c2 + 2) : c2;
                    gs += cdt[c1 * 5 + t1];
                    int idx = (tg == 0) ? 50 : ((tg & 1) ? ((tg - 1) >> 1) : (64 + ((tg - 2) >> 1)));
                    gs += S[(((t - 1) & 63) << 7) + idx];
                }
            }
        }
        __syncthreads();
    }
#undef PHASE

    if (wave == 0) {
        if (nfull == nper) { xO = NOp * rscp; }    // no tail period ran: finish here
        // forward = accF + ln2*accE + ln( sum_j x_j * exp(stop_j) )
        float W = actm * (xB * __expf(stop_t[aB]) + xI * __expf(stop_t[aI]));
        float tot = wsum64(W) + xO * __expf(stop_t[0]);
        float fwd = accF + 0.69314718055994530942f * (float)accE + __logf(tot);
        if (l == 0) res[0] = fwd;
    } else if (wave == 2) {
        // final chunk (nper-1): its rows are still intact after the loop
        if (l < CHUNK) {
            int t = 1 + (nper - 1) * CHUNK + l;
            if (t >= 1 && t <= nsteps) {
                int tg = tb[t], tp = tb[t - 1];
                int c1 = (tp == 0) ? 0 : ((tp & 1) ? 1 : 2);
                int c2 = (tg == 0) ? 0 : ((tg & 1) ? 1 : 2);
                int si = (tp - 1) >> 1, sj = (tg - 1) >> 1;
                int t1 = (tp != 0 && si != sj) ? ((c2 == 0) ? 0 : c2 + 2) : c2;
                gs += cdt[c1 * 5 + t1];
                int idx = (tg == 0) ? 50 : ((tg & 1) ? ((tg - 1) >> 1) : (64 + ((tg - 2) >> 1)));
                gs += S[(((t - 1) & 63) << 7) + idx];
            }
        }
        float gold = wsum64(gs);
        if (l == 0) res[1] = gold + stop_t[tb[len - 1]];
    }
    __syncthreads();
    if (tid == 0) out[b] = res[0] - res[1];
}

extern "C" void kernel_launch(void* const* d_in, const int* in_sizes, int n_in,
                              void* d_out, int out_size, void* d_ws, size_t ws_size,
                              hipStream_t stream) {
    const float* feats   = (const float*)d_in[0];
    const float* cdt     = (const float*)d_in[1];
    const float* start_t = (const float*)d_in[2];
    const float* stop_t  = (const float*)d_in[3];
    const int*   mask    = (const int*)d_in[4];
    const int*   tags    = (const int*)d_in[5];
    float* out = (float*)d_out;

    crf_nll_kernel<<<256, 192, 0, stream>>>(feats, cdt, start_t, stop_t, mask, tags, out);
}